// Round 6
// baseline (150.320 us; speedup 1.0000x reference)
//
#include <hip/hip_runtime.h>
#include <math.h>

#define IMG    512
#define IMG2   (IMG*IMG)
#define TC     64
#define TR     32
#define ECC    72              // TC + 8 extended columns
#define PITCH  33              // rows per column incl. dump row 32
#define NBATCH 32
#define NBLOCKS ((IMG/TC)*(IMG/TR)*NBATCH)   // 4096
#define NPIX   8388608.0f

typedef unsigned int u32;

// RNE pack: dst.lo16 = bf16(a), dst.hi16 = bf16(b)
__device__ __forceinline__ u32 pk_bf16(float a, float b) {
    float r;
    asm("v_cvt_pk_bf16_f32 %0, %1, %2" : "=v"(r) : "v"(a), "v"(b));
    return __float_as_uint(r);
}
__device__ __forceinline__ float lo16(u32 x) { return __uint_as_float(x << 16); }
__device__ __forceinline__ float hi16(u32 x) { return __uint_as_float(x & 0xffff0000u); }

__global__ __launch_bounds__(256, 5)
void lncc_main(const float* __restrict__ Tm, const float* __restrict__ Im,
               float* __restrict__ ws)
{
    // ws[0] = arrival counter (memset to 0 each launch); ws[64..] = partials
    u32*   cnt     = (u32*)ws;
    float* partial = ws + 64;

    // 12 B/entry column sums, split so pass-2 column reads are conflict-free:
    //   AB: uint2 {pk(w0,w1), pk(w2,w3)}  bank = 2*(ec+row) mod 32 -> 2-way (free)
    //   Cc: u32   pk(w4,w4)               bank = (ec+row) mod 32   -> conflict-free
    __shared__ uint2 AB[ECC * PITCH];      // 19,008 B
    __shared__ u32   Cc[ECC * PITCH];      //  9,504 B
    __shared__ float wsum[4];
    __shared__ int   lastFlag;

    const int tid = threadIdx.x;
    const int x0 = blockIdx.x * TC;
    const int y0 = blockIdx.y * TR;
    const size_t base = (size_t)blockIdx.z * IMG2;
    const float* tb = Tm + base;
    const float* ib = Im + base;

    const bool interior = (blockIdx.x - 1u < 6u) & (blockIdx.y - 1u < 14u);

    // ---- Pass 1: vertical sliding 9-sums; 3 strips x 72 columns, 19 iters ----
    if (tid < 3 * ECC) {
        const int ec    = tid % ECC;
        const int strip = tid / ECC;        // 0,1,2
        const int r0    = strip * 11;       // strip2 writes row 32 = dump slot

        float rt[9], rv[9];
        float s0 = 0.f, s1 = 0.f, s2 = 0.f, s3 = 0.f, s4 = 0.f;

        if (interior) {
            const int off0 = (y0 + r0 - 4) * IMG + (x0 + ec - 4);
            const float* tp = tb + off0;
            const float* ip = ib + off0;
            #pragma unroll
            for (int j = 0; j < 19; ++j) {
                const float t = tp[j * IMG];
                const float v = ip[j * IMG];
                s0 += t; s1 += v;
                s2 = fmaf(t, t, s2); s3 = fmaf(v, v, s3); s4 = fmaf(t, v, s4);
                rt[j % 9] = t; rv[j % 9] = v;
                if (j >= 8) {
                    const int idx = ec * PITCH + r0 + (j - 8);
                    AB[idx] = make_uint2(pk_bf16(s0, s1), pk_bf16(s2, s3));
                    Cc[idx] = pk_bf16(s4, s4);
                    const float ot = rt[(j - 8) % 9], ov = rv[(j - 8) % 9];
                    s0 -= ot; s1 -= ov;
                    s2 = fmaf(-ot, ot, s2); s3 = fmaf(-ov, ov, s3); s4 = fmaf(-ot, ov, s4);
                }
            }
        } else {
            const int gx   = x0 + ec - 4;
            const float xm = ((unsigned)gx < IMG) ? 1.0f : 0.0f;
            const int gxc  = gx < 0 ? 0 : (gx > IMG - 1 ? IMG - 1 : gx);
            const int Y    = y0 + r0 - 4;
            #pragma unroll
            for (int j = 0; j < 19; ++j) {
                const int gy  = Y + j;
                const float m = ((unsigned)gy < IMG) ? xm : 0.0f;
                const int gyc = gy < 0 ? 0 : (gy > IMG - 1 ? IMG - 1 : gy);
                const int off = (gyc << 9) + gxc;
                const float t = tb[off] * m;
                const float v = ib[off] * m;
                s0 += t; s1 += v;
                s2 = fmaf(t, t, s2); s3 = fmaf(v, v, s3); s4 = fmaf(t, v, s4);
                rt[j % 9] = t; rv[j % 9] = v;
                if (j >= 8) {
                    const int idx = ec * PITCH + r0 + (j - 8);
                    AB[idx] = make_uint2(pk_bf16(s0, s1), pk_bf16(s2, s3));
                    Cc[idx] = pk_bf16(s4, s4);
                    const float ot = rt[(j - 8) % 9], ov = rv[(j - 8) % 9];
                    s0 -= ot; s1 -= ov;
                    s2 = fmaf(-ot, ot, s2); s3 = fmaf(-ov, ov, s3); s4 = fmaf(-ot, ov, s4);
                }
            }
        }
    }
    __syncthreads();

    // ---- Pass 2: horizontal sliding 9-sums + score; 32 rows x 8 segments ----
    float lsum = 0.f;
    {
        const int row = tid & 31;
        const int b0  = (tid >> 5) * 8 * PITCH + row;
        float W0 = 0.f, W1 = 0.f, W2 = 0.f, W3 = 0.f, W4 = 0.f;
        float r0_[9], r1_[9], r2_[9], r3_[9], r4_[9];   // unpacked ring
        const float inv81 = 1.0f / 81.0f;

        #pragma unroll
        for (int k = 0; k < 16; ++k) {
            const uint2 ab = AB[b0 + k * PITCH];
            const u32   c  = Cc[b0 + k * PITCH];
            const float h0 = lo16(ab.x), h1 = hi16(ab.x);
            const float h2 = lo16(ab.y), h3 = hi16(ab.y);
            const float h4 = hi16(c);
            W0 += h0; W1 += h1; W2 += h2; W3 += h3; W4 += h4;
            const int ri = k % 9;
            r0_[ri] = h0; r1_[ri] = h1; r2_[ri] = h2; r3_[ri] = h3; r4_[ri] = h4;
            if (k >= 8) {
                const float t0 = W0 * inv81;
                const float t1 = W1 * inv81;
                const float cross = fmaf(-t0, W1, W4);
                const float Iv    = fmaf(-t0, W0, W2);
                const float Jv    = fmaf(-t1, W1, W3);
                const float den   = fmaf(Iv, Jv, 1e-12f);
                lsum += cross * __builtin_amdgcn_rsqf(den);
                const int o = (k - 8) % 9;
                W0 -= r0_[o]; W1 -= r1_[o]; W2 -= r2_[o]; W3 -= r3_[o]; W4 -= r4_[o];
            }
        }
    }

    // ---- deterministic block reduction ----
    #pragma unroll
    for (int d = 32; d >= 1; d >>= 1) lsum += __shfl_down(lsum, d, 64);
    if ((tid & 63) == 0) wsum[tid >> 6] = lsum;
    __syncthreads();
    if (tid == 0) {
        const int bid = (blockIdx.z * gridDim.y + blockIdx.y) * gridDim.x + blockIdx.x;
        partial[bid] = wsum[0] + wsum[1] + wsum[2] + wsum[3];
        __threadfence();                               // release: partial visible device-wide
        const u32 old = atomicAdd(cnt, 1u);
        lastFlag = (old == NBLOCKS - 1) ? 1 : 0;
    }
    __syncthreads();

    // ---- last arriving block: final reduction in fixed index order ----
    if (lastFlag) {
        __threadfence();                               // acquire: see all partials
        float s = 0.f;
        #pragma unroll
        for (int i = 0; i < NBLOCKS / 256; ++i) s += partial[tid + i * 256];
        #pragma unroll
        for (int d = 32; d >= 1; d >>= 1) s += __shfl_down(s, d, 64);
        if ((tid & 63) == 0) wsum[tid >> 6] = s;
        __syncthreads();
        if (tid == 0) {
            float* out = partial - 32;                 // ws[32] = output slot
            out[0] = 1.0f - (wsum[0] + wsum[1] + wsum[2] + wsum[3]) / NPIX;
        }
    }
}

// Tiny copy kernel: move result from ws to d_out (keeps d_out write simple &
// avoids the last block needing d_out's pointer-aliasing assumptions).
__global__ void lncc_copy(const float* __restrict__ ws, float* __restrict__ out)
{
    out[0] = ws[32];
}

extern "C" void kernel_launch(void* const* d_in, const int* in_sizes, int n_in,
                              void* d_out, int out_size, void* d_ws, size_t ws_size,
                              hipStream_t stream)
{
    (void)in_sizes; (void)n_in; (void)out_size; (void)ws_size;
    const float* Tm = (const float*)d_in[0];   // template
    const float* Im = (const float*)d_in[1];   // image
    float* ws = (float*)d_ws;                  // [0]=counter, [32]=result, [64..]=partials

    hipMemsetAsync(d_ws, 0, 4, stream);        // zero arrival counter (memset node)
    dim3 grid(IMG / TC, IMG / TR, NBATCH);     // (8, 16, 32)
    lncc_main<<<grid, 256, 0, stream>>>(Tm, Im, ws);
    lncc_copy<<<1, 1, 0, stream>>>(ws, (float*)d_out);
}

// Round 7
// 27.408 us; speedup vs baseline: 5.4846x; 5.4846x over previous
//
#include <hip/hip_runtime.h>
#include <math.h>

#define IMG    512
#define IMG2   (IMG*IMG)
#define TC     64
#define TR     32
#define ECC    72              // TC + 8 extended columns
#define PITCH  33              // rows per column incl. dump row 32
#define NBATCH 32
#define NBLOCKS ((IMG/TC)*(IMG/TR)*NBATCH)   // 4096
#define NPIX   8388608.0f

typedef unsigned int u32;

// RNE pack: dst.lo16 = bf16(a), dst.hi16 = bf16(b)
__device__ __forceinline__ u32 pk_bf16(float a, float b) {
    float r;
    asm("v_cvt_pk_bf16_f32 %0, %1, %2" : "=v"(r) : "v"(a), "v"(b));
    return __float_as_uint(r);
}
__device__ __forceinline__ float lo16(u32 x) { return __uint_as_float(x << 16); }
__device__ __forceinline__ float hi16(u32 x) { return __uint_as_float(x & 0xffff0000u); }

__global__ __launch_bounds__(256, 5)
void lncc_main(const float* __restrict__ Tm, const float* __restrict__ Im,
               float* __restrict__ partial)
{
    // 12 B/entry column sums, split so pass-2 column reads are conflict-free:
    //   AB: uint2 {pk(w0,w1), pk(w2,w3)}  bank = 2*(ec+row) mod 32 -> 2-way (free)
    //   Cc: u32   pk(w4,w4)               bank = (ec+row) mod 32   -> conflict-free
    __shared__ uint2 AB[ECC * PITCH];      // 19,008 B
    __shared__ u32   Cc[ECC * PITCH];      //  9,504 B
    __shared__ float wsum[4];

    const int tid = threadIdx.x;
    const int x0 = blockIdx.x * TC;
    const int y0 = blockIdx.y * TR;
    const size_t base = (size_t)blockIdx.z * IMG2;
    const float* tb = Tm + base;
    const float* ib = Im + base;

    const bool interior = (blockIdx.x - 1u < 6u) & (blockIdx.y - 1u < 14u);

    // ---- Pass 1: vertical sliding 9-sums; 3 strips x 72 columns ----
    // Phase split: prefetch ALL 19x2 rows into registers (full MLP, one
    // memory-latency), then accumulate/pack/store purely from registers.
    if (tid < 3 * ECC) {
        const int ec    = tid % ECC;
        const int strip = tid / ECC;        // 0,1,2
        const int r0    = strip * 11;       // strip2 writes row 32 = dump slot

        float tv_[19], vv_[19];

        if (interior) {
            const int off0 = (y0 + r0 - 4) * IMG + (x0 + ec - 4);
            const float* tp = tb + off0;
            const float* ip = ib + off0;
            #pragma unroll
            for (int j = 0; j < 19; ++j) {
                tv_[j] = tp[j * IMG];
                vv_[j] = ip[j * IMG];
            }
        } else {
            const int gx   = x0 + ec - 4;
            const float xm = ((unsigned)gx < IMG) ? 1.0f : 0.0f;
            const int gxc  = gx < 0 ? 0 : (gx > IMG - 1 ? IMG - 1 : gx);
            const int Y    = y0 + r0 - 4;
            #pragma unroll
            for (int j = 0; j < 19; ++j) {
                const int gy  = Y + j;
                const float m = ((unsigned)gy < IMG) ? xm : 0.0f;
                const int gyc = gy < 0 ? 0 : (gy > IMG - 1 ? IMG - 1 : gy);
                const int off = (gyc << 9) + gxc;
                tv_[j] = tb[off] * m;
                vv_[j] = ib[off] * m;
            }
        }

        float s0 = 0.f, s1 = 0.f, s2 = 0.f, s3 = 0.f, s4 = 0.f;
        #pragma unroll
        for (int j = 0; j < 19; ++j) {
            const float t = tv_[j], v = vv_[j];
            s0 += t; s1 += v;
            s2 = fmaf(t, t, s2); s3 = fmaf(v, v, s3); s4 = fmaf(t, v, s4);
            if (j >= 8) {
                const int idx = ec * PITCH + r0 + (j - 8);
                AB[idx] = make_uint2(pk_bf16(s0, s1), pk_bf16(s2, s3));
                Cc[idx] = pk_bf16(s4, s4);
                const float ot = tv_[j - 8], ov = vv_[j - 8];
                s0 -= ot; s1 -= ov;
                s2 = fmaf(-ot, ot, s2); s3 = fmaf(-ov, ov, s3); s4 = fmaf(-ot, ov, s4);
            }
        }
    }
    __syncthreads();

    // ---- Pass 2: horizontal sliding 9-sums + score; 32 rows x 8 segments ----
    float lsum = 0.f;
    {
        const int row = tid & 31;
        const int b0  = (tid >> 5) * 8 * PITCH + row;
        float W0 = 0.f, W1 = 0.f, W2 = 0.f, W3 = 0.f, W4 = 0.f;
        float r0_[9], r1_[9], r2_[9], r3_[9], r4_[9];   // unpacked ring (named regs)
        const float inv81 = 1.0f / 81.0f;

        #pragma unroll
        for (int k = 0; k < 16; ++k) {
            const uint2 ab = AB[b0 + k * PITCH];
            const u32   c  = Cc[b0 + k * PITCH];
            const float h0 = lo16(ab.x), h1 = hi16(ab.x);
            const float h2 = lo16(ab.y), h3 = hi16(ab.y);
            const float h4 = hi16(c);
            W0 += h0; W1 += h1; W2 += h2; W3 += h3; W4 += h4;
            const int ri = k % 9;
            r0_[ri] = h0; r1_[ri] = h1; r2_[ri] = h2; r3_[ri] = h3; r4_[ri] = h4;
            if (k >= 8) {
                const float t0 = W0 * inv81;
                const float t1 = W1 * inv81;
                const float cross = fmaf(-t0, W1, W4);
                const float Iv    = fmaf(-t0, W0, W2);
                const float Jv    = fmaf(-t1, W1, W3);
                const float den   = fmaf(Iv, Jv, 1e-12f);
                lsum = fmaf(cross, __builtin_amdgcn_rsqf(den), lsum);
                const int o = (k - 8) % 9;
                W0 -= r0_[o]; W1 -= r1_[o]; W2 -= r2_[o]; W3 -= r3_[o]; W4 -= r4_[o];
            }
        }
    }

    // ---- deterministic block reduction ----
    #pragma unroll
    for (int d = 32; d >= 1; d >>= 1) lsum += __shfl_down(lsum, d, 64);
    if ((tid & 63) == 0) wsum[tid >> 6] = lsum;
    __syncthreads();
    if (tid == 0) {
        const int bid = (blockIdx.z * gridDim.y + blockIdx.y) * gridDim.x + blockIdx.x;
        partial[bid] = wsum[0] + wsum[1] + wsum[2] + wsum[3];
    }
}

__global__ __launch_bounds__(256)
void lncc_reduce(const float* __restrict__ partial, float* __restrict__ out)
{
    __shared__ float ws[4];
    const int tid = threadIdx.x;
    float s = 0.f;
    #pragma unroll
    for (int i = 0; i < NBLOCKS / 256; ++i) s += partial[tid + i * 256];
    #pragma unroll
    for (int d = 32; d >= 1; d >>= 1) s += __shfl_down(s, d, 64);
    if ((tid & 63) == 0) ws[tid >> 6] = s;
    __syncthreads();
    if (tid == 0) out[0] = 1.0f - (ws[0] + ws[1] + ws[2] + ws[3]) / NPIX;
}

extern "C" void kernel_launch(void* const* d_in, const int* in_sizes, int n_in,
                              void* d_out, int out_size, void* d_ws, size_t ws_size,
                              hipStream_t stream)
{
    (void)in_sizes; (void)n_in; (void)out_size; (void)ws_size;
    const float* Tm = (const float*)d_in[0];   // template
    const float* Im = (const float*)d_in[1];   // image
    float* out  = (float*)d_out;
    float* part = (float*)d_ws;                // NBLOCKS floats of scratch

    dim3 grid(IMG / TC, IMG / TR, NBATCH);     // (8, 16, 32)
    lncc_main<<<grid, 256, 0, stream>>>(Tm, Im, part);
    lncc_reduce<<<1, 256, 0, stream>>>(part, out);
}